// Round 12
// baseline (18.605 us; speedup 1.0000x reference)
//
#include <hip/hip_runtime.h>
#include <hip/hip_bf16.h>
#include <math.h>

#define DD 64  // feature dim

typedef __bf16 bf16x4 __attribute__((ext_vector_type(4)));
typedef __bf16 bf16x8 __attribute__((ext_vector_type(8)));
typedef float f32x4 __attribute__((ext_vector_type(4)));

// Kernel A: fp32 -> bf16 conversion + row norms of the bf16-ROUNDED values
// (so d^2 = nx+ny-2*dot = ||xb-yb||^2 >= 0 up to MFMA rounding).
// 16 threads per row (float4 each), 16 rows per 256-thread block.
__global__ __launch_bounds__(256) void convert_norm(
    const float* __restrict__ x, const float* __restrict__ y,
    __hip_bfloat16* __restrict__ xb, __hip_bfloat16* __restrict__ yb,
    float* __restrict__ nx, float* __restrict__ ny, int N, int M) {
  const int tid = threadIdx.x;
  const int r   = blockIdx.x * 16 + (tid >> 4);  // global row (x rows then y)
  const int c   = (tid & 15) * 4;                // element offset within row

  const float* src;
  __hip_bfloat16* dst;
  float* nrm;
  int rr = r;
  if (r < N) {
    src = x; dst = xb; nrm = nx;
  } else {
    rr = r - N;
    if (rr >= M) return;
    src = y; dst = yb; nrm = ny;
  }

  const float4 v = *reinterpret_cast<const float4*>(&src[(size_t)rr * DD + c]);
  bf16x4 b;
  float s = 0.f, t;
  b[0] = (__bf16)v.x; t = (float)b[0]; s = fmaf(t, t, s);
  b[1] = (__bf16)v.y; t = (float)b[1]; s = fmaf(t, t, s);
  b[2] = (__bf16)v.z; t = (float)b[2]; s = fmaf(t, t, s);
  b[3] = (__bf16)v.w; t = (float)b[3]; s = fmaf(t, t, s);
  *reinterpret_cast<bf16x4*>(&dst[(size_t)rr * DD + c]) = b;

  // Reduce across the 16 lanes of this row (lanes share a 16-lane group).
  s += __shfl_xor(s, 1, 16);
  s += __shfl_xor(s, 2, 16);
  s += __shfl_xor(s, 4, 16);
  s += __shfl_xor(s, 8, 16);
  if ((tid & 15) == 0) nrm[rr] = s;
}

// Kernel B: out[i][j] = sqrt(max(nx[i] + ny[j] - 2 * xb_i.yb_j, 0)).
// HIGH-OCCUPANCY geometry: each wave owns a 16x32 tile -> 8192 waves =
// 8 waves/SIMD (R9 showed the pipeline is latency-bound with SIMDs ~90%
// idle at 4 waves/SIMD). Per-wave work is minimal: 3 bf16 fragment loads,
// 2 norm loads, 4 MFMA, 8 fma+sqrt, 2 nontemporal float4 stores.
// Swapped-operand MFMA (y as A, x as B): C/D row->j, col->i, so each
// lane's 4 acc regs are 4 consecutive j.
__global__ __launch_bounds__(256) void cdist_main(
    const __hip_bfloat16* __restrict__ xb, const __hip_bfloat16* __restrict__ yb,
    const float* __restrict__ nx, const float* __restrict__ ny,
    float* __restrict__ out, int M) {
  // Bijective XCD swizzle: 2048 blocks, 8 XCDs -> 256 consecutive per XCD.
  const int bid = blockIdx.x;
  const int swz = (bid & 7) * 256 + (bid >> 3);
  const int bx = swz & 31;   // j-tile (64 cols)
  const int by = swz >> 5;   // i-tile (32 rows)

  const int lane = threadIdx.x & 63;
  const int wid  = threadIdx.x >> 6;      // 0..3
  const int wr = wid >> 1, wc = wid & 1;  // 2x2 wave grid
  const int i0 = by * 32 + wr * 16;       // wave's x-row base (16 rows)
  const int j0 = bx * 64 + wc * 32;       // wave's y-row base (32 rows)
  const int lrow = lane & 15;
  const int kgrp = lane >> 4;

  // A/B layout: lane l holds 8 contiguous k-elems of row (l&15) at k-offset
  // (l>>4)*8 (+32 per k-step). One dwordx4 load per fragment.
  const __hip_bfloat16* pa = &xb[(size_t)(i0 + lrow) * DD + kgrp * 8];
  bf16x8 a[2];
  a[0] = *reinterpret_cast<const bf16x8*>(pa);
  a[1] = *reinterpret_cast<const bf16x8*>(pa + 32);
  bf16x8 b[2][2];
  #pragma unroll
  for (int n = 0; n < 2; ++n) {
    const __hip_bfloat16* pb = &yb[(size_t)(j0 + n * 16 + lrow) * DD + kgrp * 8];
    b[n][0] = *reinterpret_cast<const bf16x8*>(pb);
    b[n][1] = *reinterpret_cast<const bf16x8*>(pb + 32);
  }

  // Norms via direct cached loads -- no cross-lane ops.
  const float nxa = nx[i0 + lrow];
  float4 nyv[2];
  #pragma unroll
  for (int n = 0; n < 2; ++n)
    nyv[n] = *reinterpret_cast<const float4*>(&ny[j0 + n * 16 + kgrp * 4]);

  // Swapped-operand MFMA: D[row -> j][col -> i].
  f32x4 acc[2] = {};
  #pragma unroll
  for (int ks = 0; ks < 2; ++ks)
    #pragma unroll
    for (int n = 0; n < 2; ++n)
      acc[n] = __builtin_amdgcn_mfma_f32_16x16x32_bf16(
          b[n][ks], a[ks], acc[n], 0, 0, 0);

  // Epilogue: i = i0 + lrow, j = j0 + n*16 + kgrp*4 + r.
  #pragma unroll
  for (int n = 0; n < 2; ++n) {
    f32x4 res;
    float d2;
    d2 = fmaf(-2.0f, acc[n][0], nxa + nyv[n].x);
    res[0] = __builtin_amdgcn_sqrtf(fmaxf(d2, 0.f));
    d2 = fmaf(-2.0f, acc[n][1], nxa + nyv[n].y);
    res[1] = __builtin_amdgcn_sqrtf(fmaxf(d2, 0.f));
    d2 = fmaf(-2.0f, acc[n][2], nxa + nyv[n].z);
    res[2] = __builtin_amdgcn_sqrtf(fmaxf(d2, 0.f));
    d2 = fmaf(-2.0f, acc[n][3], nxa + nyv[n].w);
    res[3] = __builtin_amdgcn_sqrtf(fmaxf(d2, 0.f));
    __builtin_nontemporal_store(
        res, reinterpret_cast<f32x4*>(
            &out[(size_t)(i0 + lrow) * M + j0 + n * 16 + kgrp * 4]));
  }
}

extern "C" void kernel_launch(void* const* d_in, const int* in_sizes, int n_in,
                              void* d_out, int out_size, void* d_ws, size_t ws_size,
                              hipStream_t stream) {
  const float* x = (const float*)d_in[0];
  const float* y = (const float*)d_in[1];
  float* out = (float*)d_out;
  const int N = in_sizes[0] / DD;  // 2048
  const int M = in_sizes[1] / DD;  // 2048

  // Workspace layout (16B-aligned slices).
  char* ws = (char*)d_ws;
  __hip_bfloat16* xb = (__hip_bfloat16*)ws;                        // N*DD*2 B
  __hip_bfloat16* yb = (__hip_bfloat16*)(ws + (size_t)N * DD * 2); // M*DD*2 B
  float* nx = (float*)(ws + (size_t)(N + M) * DD * 2);             // N*4 B
  float* ny = (float*)(ws + (size_t)(N + M) * DD * 2 + (size_t)N * 4);

  // A: (N+M) rows / 16 rows per block.
  convert_norm<<<dim3((N + M) / 16), dim3(256), 0, stream>>>(
      x, y, xb, yb, nx, ny, N, M);

  // B: 2048 blocks of 4 waves; each block a 32x64 output tile.
  const int nblocks = (N / 32) * (M / 64);
  cdist_main<<<dim3(nblocks), dim3(256), 0, stream>>>(xb, yb, nx, ny, out, M);
}

// Round 13
// 13.889 us; speedup vs baseline: 1.3395x; 1.3395x over previous
//
#include <hip/hip_runtime.h>
#include <hip/hip_bf16.h>
#include <math.h>

#define DD 64  // feature dim

typedef __bf16 bf16x8 __attribute__((ext_vector_type(8)));
typedef float f32x4 __attribute__((ext_vector_type(4)));

// Convert 8 fp32 -> bf16 fragment, accumulating sum of squares of the
// bf16-ROUNDED values into s (so d^2 = nx+ny-2dot = ||xb-yb||^2 >= 0).
__device__ inline bf16x8 cvt8n(const float4 a, const float4 b, float& s) {
  bf16x8 r;
  float t;
  r[0] = (__bf16)a.x; t = (float)r[0]; s = fmaf(t, t, s);
  r[1] = (__bf16)a.y; t = (float)r[1]; s = fmaf(t, t, s);
  r[2] = (__bf16)a.z; t = (float)r[2]; s = fmaf(t, t, s);
  r[3] = (__bf16)a.w; t = (float)r[3]; s = fmaf(t, t, s);
  r[4] = (__bf16)b.x; t = (float)r[4]; s = fmaf(t, t, s);
  r[5] = (__bf16)b.y; t = (float)r[5]; s = fmaf(t, t, s);
  r[6] = (__bf16)b.z; t = (float)r[6]; s = fmaf(t, t, s);
  r[7] = (__bf16)b.w; t = (float)r[7]; s = fmaf(t, t, s);
  return r;
}

// Fused CDist, 2-tile pipelined (R11 base):
//   out[i][j] = sqrt(max(||xb_i||^2 + ||yb_j||^2 - 2 xb_i.yb_j, 0))
// 512 blocks; each block = two j-adjacent 64x64 tiles. Per wave: x frags +
// norms ONCE, then two fully-unrolled j-iterations with all y-loads issued
// up front (2x per-wave MLP; stores of iter 0 overlap compute of iter 1).
// Swapped-operand MFMA: C/D row->j, col->i -> nontemporal float4 stores.
__global__ __launch_bounds__(256) void cdist_fused(
    const float* __restrict__ x, const float* __restrict__ y,
    float* __restrict__ out, int N, int M) {
  // Bijective XCD swizzle over 512 blocks: 64 consecutive per XCD.
  const int bid = blockIdx.x;
  const int swz = (bid & 7) * 64 + (bid >> 3);
  const int bxp = swz & 15;  // j tile-PAIR index (128 cols)
  const int by  = swz >> 4;  // i tile index (64 rows)

  const int lane = threadIdx.x & 63;
  const int wid  = threadIdx.x >> 6;      // 0..3
  const int wr = wid >> 1, wc = wid & 1;  // 2x2 wave grid
  const int i0  = by * 64 + wr * 32;      // wave's x-row base (32 rows)
  const int j00 = bxp * 128 + wc * 32;    // wave's y-row base, iter 0
  const int lrow = lane & 15;
  const int kgrp = lane >> 4;

  __shared__ float sny[4][2][32];  // [wid][iter][n*16+lrow], wave-private

  // ---- x side: load + convert + norm ONCE (shared by both iterations) ----
  bf16x8 a[2][2];
  float sa[2] = {0.f, 0.f};
  #pragma unroll
  for (int m = 0; m < 2; ++m) {
    const float* px = &x[(size_t)(i0 + m * 16 + lrow) * DD + kgrp * 8];
    a[m][0] = cvt8n(*reinterpret_cast<const float4*>(px),
                    *reinterpret_cast<const float4*>(px + 4), sa[m]);
    a[m][1] = cvt8n(*reinterpret_cast<const float4*>(px + 32),
                    *reinterpret_cast<const float4*>(px + 36), sa[m]);
  }

  // ---- y side: issue ALL loads for both iterations up front ----
  float4 yv[2][2][2][2];  // [iter][n][ks][half]
  #pragma unroll
  for (int it = 0; it < 2; ++it) {
    #pragma unroll
    for (int n = 0; n < 2; ++n) {
      const float* py =
          &y[(size_t)(j00 + it * 64 + n * 16 + lrow) * DD + kgrp * 8];
      yv[it][n][0][0] = *reinterpret_cast<const float4*>(py);
      yv[it][n][0][1] = *reinterpret_cast<const float4*>(py + 4);
      yv[it][n][1][0] = *reinterpret_cast<const float4*>(py + 32);
      yv[it][n][1][1] = *reinterpret_cast<const float4*>(py + 36);
    }
  }

  // x-norm butterfly (overlaps y-load latency).
  #pragma unroll
  for (int m = 0; m < 2; ++m) {
    sa[m] += __shfl_xor(sa[m], 16, 64);
    sa[m] += __shfl_xor(sa[m], 32, 64);
  }

  // ---- two pipelined iterations ----
  #pragma unroll
  for (int it = 0; it < 2; ++it) {
    bf16x8 b[2][2];
    float sb[2] = {0.f, 0.f};
    #pragma unroll
    for (int n = 0; n < 2; ++n) {
      b[n][0] = cvt8n(yv[it][n][0][0], yv[it][n][0][1], sb[n]);
      b[n][1] = cvt8n(yv[it][n][1][0], yv[it][n][1][1], sb[n]);
    }
    #pragma unroll
    for (int n = 0; n < 2; ++n) {
      sb[n] += __shfl_xor(sb[n], 16, 64);
      sb[n] += __shfl_xor(sb[n], 32, 64);
    }
    if (kgrp == 0) {
      sny[wid][it][lrow]      = sb[0];
      sny[wid][it][16 + lrow] = sb[1];
    }

    f32x4 acc[2][2] = {};  // acc[n][m]
    #pragma unroll
    for (int ks = 0; ks < 2; ++ks)
      #pragma unroll
      for (int n = 0; n < 2; ++n)
        #pragma unroll
        for (int m = 0; m < 2; ++m)
          acc[n][m] = __builtin_amdgcn_mfma_f32_16x16x32_bf16(
              b[n][ks], a[m][ks], acc[n][m], 0, 0, 0);

    const int j0 = j00 + it * 64;
    #pragma unroll
    for (int n = 0; n < 2; ++n) {
      const float4 nyv =
          *reinterpret_cast<const float4*>(&sny[wid][it][n * 16 + kgrp * 4]);
      #pragma unroll
      for (int m = 0; m < 2; ++m) {
        f32x4 res;
        float d2;
        d2 = fmaf(-2.0f, acc[n][m][0], sa[m] + nyv.x);
        res[0] = __builtin_amdgcn_sqrtf(fmaxf(d2, 0.f));
        d2 = fmaf(-2.0f, acc[n][m][1], sa[m] + nyv.y);
        res[1] = __builtin_amdgcn_sqrtf(fmaxf(d2, 0.f));
        d2 = fmaf(-2.0f, acc[n][m][2], sa[m] + nyv.z);
        res[2] = __builtin_amdgcn_sqrtf(fmaxf(d2, 0.f));
        d2 = fmaf(-2.0f, acc[n][m][3], sa[m] + nyv.w);
        res[3] = __builtin_amdgcn_sqrtf(fmaxf(d2, 0.f));
        __builtin_nontemporal_store(
            res, reinterpret_cast<f32x4*>(
                &out[(size_t)(i0 + m * 16 + lrow) * M + j0 + n * 16 + kgrp * 4]));
      }
    }
  }
}

extern "C" void kernel_launch(void* const* d_in, const int* in_sizes, int n_in,
                              void* d_out, int out_size, void* d_ws, size_t ws_size,
                              hipStream_t stream) {
  const float* x = (const float*)d_in[0];
  const float* y = (const float*)d_in[1];
  float* out = (float*)d_out;
  const int N = in_sizes[0] / DD;  // 2048
  const int M = in_sizes[1] / DD;  // 2048

  // 32 i-tiles x 16 j-tile-pairs = 512 blocks.
  const int nblocks = (N / 64) * (M / 128);
  cdist_fused<<<dim3(nblocks), dim3(256), 0, stream>>>(x, y, out, N, M);
}

// Round 14
// 13.615 us; speedup vs baseline: 1.3665x; 1.0202x over previous
//
#include <hip/hip_runtime.h>
#include <hip/hip_bf16.h>
#include <math.h>

#define DD 64  // feature dim

typedef __bf16 bf16x8 __attribute__((ext_vector_type(8)));
typedef float f32x4 __attribute__((ext_vector_type(4)));

// Convert 8 fp32 -> bf16 fragment, accumulating sum of squares of the
// bf16-ROUNDED values into s (so d^2 = nx+ny-2dot = ||xb-yb||^2 >= 0).
__device__ inline bf16x8 cvt8n(const float4 a, const float4 b, float& s) {
  bf16x8 r;
  float t;
  r[0] = (__bf16)a.x; t = (float)r[0]; s = fmaf(t, t, s);
  r[1] = (__bf16)a.y; t = (float)r[1]; s = fmaf(t, t, s);
  r[2] = (__bf16)a.z; t = (float)r[2]; s = fmaf(t, t, s);
  r[3] = (__bf16)a.w; t = (float)r[3]; s = fmaf(t, t, s);
  r[4] = (__bf16)b.x; t = (float)r[4]; s = fmaf(t, t, s);
  r[5] = (__bf16)b.y; t = (float)r[5]; s = fmaf(t, t, s);
  r[6] = (__bf16)b.z; t = (float)r[6]; s = fmaf(t, t, s);
  r[7] = (__bf16)b.w; t = (float)r[7]; s = fmaf(t, t, s);
  return r;
}

// Fused CDist, max work-per-wave geometry:
//   out[i][j] = sqrt(max(||xb_i||^2 + ||yb_j||^2 - 2 xb_i.yb_j, 0))
// 256 blocks of 128x128 -> EXACTLY one block per CU (no scheduling tail).
// Each wave owns a 64x64 tile: 4x4 fragments, 32 MFMAs; x/y fragments are
// converted once and reused 4x (R13 lesson: fatter waves + less staging per
// output wins). One wide independent load burst per wave (24 dwordx4/lane).
// Swapped-operand MFMA: C/D row->j, col->i -> nontemporal float4 stores.
__global__ __launch_bounds__(256) void cdist_fused(
    const float* __restrict__ x, const float* __restrict__ y,
    float* __restrict__ out, int N, int M) {
  // Bijective XCD swizzle: 256 blocks, 8 XCDs -> 32 consecutive per XCD.
  const int bid = blockIdx.x;
  const int swz = (bid & 7) * 32 + (bid >> 3);
  const int bx = swz & 15;   // j tile (128 cols)
  const int by = swz >> 4;   // i tile (128 rows)

  const int lane = threadIdx.x & 63;
  const int wid  = threadIdx.x >> 6;      // 0..3
  const int wr = wid >> 1, wc = wid & 1;  // 2x2 wave grid
  const int i0 = by * 128 + wr * 64;      // wave's x-row base (64 rows)
  const int j0 = bx * 128 + wc * 64;      // wave's y-row base (64 rows)
  const int lrow = lane & 15;
  const int kgrp = lane >> 4;

  __shared__ float sny[4][64];  // per-wave y-norms [wid][n*16 + lrow]

  // Fragment loads (fp32 global -> bf16 regs) + partial norms.
  // A/B layout: lane l holds 8 contiguous k-elems of row (l&15) at k-offset
  // (l>>4)*8 (+32 per k-step). Verified rounds 2-13.
  bf16x8 a[4][2], b[4][2];
  float sa[4], sb[4];
  #pragma unroll
  for (int m = 0; m < 4; ++m) {
    const float* px = &x[(size_t)(i0 + m * 16 + lrow) * DD + kgrp * 8];
    sa[m] = 0.f;
    a[m][0] = cvt8n(*reinterpret_cast<const float4*>(px),
                    *reinterpret_cast<const float4*>(px + 4), sa[m]);
    a[m][1] = cvt8n(*reinterpret_cast<const float4*>(px + 32),
                    *reinterpret_cast<const float4*>(px + 36), sa[m]);
  }
  #pragma unroll
  for (int n = 0; n < 4; ++n) {
    const float* py = &y[(size_t)(j0 + n * 16 + lrow) * DD + kgrp * 8];
    sb[n] = 0.f;
    b[n][0] = cvt8n(*reinterpret_cast<const float4*>(py),
                    *reinterpret_cast<const float4*>(py + 4), sb[n]);
    b[n][1] = cvt8n(*reinterpret_cast<const float4*>(py + 32),
                    *reinterpret_cast<const float4*>(py + 36), sb[n]);
  }

  // Butterfly over kgrp bits: full norm of row (base + g*16 + lrow) per lane.
  #pragma unroll
  for (int m = 0; m < 4; ++m) {
    sa[m] += __shfl_xor(sa[m], 16, 64);
    sa[m] += __shfl_xor(sa[m], 32, 64);
  }
  #pragma unroll
  for (int n = 0; n < 4; ++n) {
    sb[n] += __shfl_xor(sb[n], 16, 64);
    sb[n] += __shfl_xor(sb[n], 32, 64);
  }

  // Publish y-norms to wave-private LDS (kgrp==0 lanes hold lrow = j-offset).
  if (kgrp == 0) {
    #pragma unroll
    for (int n = 0; n < 4; ++n) sny[wid][n * 16 + lrow] = sb[n];
  }

  // Swapped-operand MFMA: D[row -> j][col -> i]. 32 MFMAs.
  f32x4 acc[4][4] = {};  // acc[n][m]
  #pragma unroll
  for (int ks = 0; ks < 2; ++ks)
    #pragma unroll
    for (int n = 0; n < 4; ++n)
      #pragma unroll
      for (int m = 0; m < 4; ++m)
        acc[n][m] = __builtin_amdgcn_mfma_f32_16x16x32_bf16(
            b[n][ks], a[m][ks], acc[n][m], 0, 0, 0);

  // Epilogue: element (m, n, reg r): i = i0 + m*16 + lrow (x-norm = own
  // sa[m]); j = j0 + n*16 + kgrp*4 + r (y-norms: one float4 LDS read).
  #pragma unroll
  for (int n = 0; n < 4; ++n) {
    const float4 nyv =
        *reinterpret_cast<const float4*>(&sny[wid][n * 16 + kgrp * 4]);
    #pragma unroll
    for (int m = 0; m < 4; ++m) {
      f32x4 res;
      float d2;
      d2 = fmaf(-2.0f, acc[n][m][0], sa[m] + nyv.x);
      res[0] = __builtin_amdgcn_sqrtf(fmaxf(d2, 0.f));
      d2 = fmaf(-2.0f, acc[n][m][1], sa[m] + nyv.y);
      res[1] = __builtin_amdgcn_sqrtf(fmaxf(d2, 0.f));
      d2 = fmaf(-2.0f, acc[n][m][2], sa[m] + nyv.z);
      res[2] = __builtin_amdgcn_sqrtf(fmaxf(d2, 0.f));
      d2 = fmaf(-2.0f, acc[n][m][3], sa[m] + nyv.w);
      res[3] = __builtin_amdgcn_sqrtf(fmaxf(d2, 0.f));
      __builtin_nontemporal_store(
          res, reinterpret_cast<f32x4*>(
              &out[(size_t)(i0 + m * 16 + lrow) * M + j0 + n * 16 + kgrp * 4]));
    }
  }
}

extern "C" void kernel_launch(void* const* d_in, const int* in_sizes, int n_in,
                              void* d_out, int out_size, void* d_ws, size_t ws_size,
                              hipStream_t stream) {
  const float* x = (const float*)d_in[0];
  const float* y = (const float*)d_in[1];
  float* out = (float*)d_out;
  const int N = in_sizes[0] / DD;  // 2048
  const int M = in_sizes[1] / DD;  // 2048

  // 16 x 16 tiles of 128x128 = 256 blocks = 1 per CU.
  const int nblocks = (N / 128) * (M / 128);
  cdist_fused<<<dim3(nblocks), dim3(256), 0, stream>>>(x, y, out, N, M);
}